// Round 4
// baseline (211.645 us; speedup 1.0000x reference)
//
#include <hip/hip_runtime.h>
#include <math.h>

// Problem constants (from reference): B=64, Q=900, T=128, NUM_CLASSES=13
#define B_    64
#define Q_    900
#define T_    128
#define NCLS  13
#define NCLS1 14
#define NTH   256
#define NWV   (NTH / 64)
#define NK    15          // columns per lane (wave0): q = lane + 64*k
#define FRSZ  384         // free-row ring: <=128 initial + <=256 ARR displacements

// Block-wide f64 sum; result valid on tid 0. All threads must call.
__device__ __forceinline__ double blockSum(double v, double* sAcc, int tid) {
#pragma unroll
    for (int off = 32; off > 0; off >>= 1) v += __shfl_down(v, off);
    if ((tid & 63) == 0) sAcc[tid >> 6] = v;
    __syncthreads();
    if (tid == 0) {
#pragma unroll
        for (int w = 1; w < NWV; ++w) v += sAcc[w];
    }
    __syncthreads();
    return v;
}

// f32 cost entry, bit-identical op order to the jnp reference:
// (-prob[lab]) + (|dx|+|dy|+|dz|+|dw|) summed left-to-right.
__device__ __forceinline__ float costQ(const float4 p4, const float4 t4, const float pr) {
    float cb = fabsf(p4.x - t4.x);
    cb = cb + fabsf(p4.y - t4.y);
    cb = cb + fabsf(p4.z - t4.z);
    cb = cb + fabsf(p4.w - t4.w);
    return cb - pr;
}

// One block per image. Staging + row-minima use all 256 threads; the serial
// matching (greedy init -> augmenting-row-reduction -> SSP Dijkstra) runs on
// wave 0 only with per-column duals/minv/used in registers and NO barriers
// (single-wave DS ops are in-order). All phases preserve dual feasibility +
// matched-edge tightness, so the unique optimal assignment (== reference's
// e-maxx JV result on the same f32 cost entries) is returned.
extern "C" __global__ __launch_bounds__(NTH, 1)
void detr_hungarian_loss(const float* __restrict__ pc,    // [B,Q,14]
                         const float* __restrict__ pbx,   // [B,Q,4]
                         const int*   __restrict__ tl,    // [B,T]
                         const float* __restrict__ tbx,   // [B,T,4]
                         double* __restrict__ perImg)     // [B]
{
    const int b   = blockIdx.x;
    const int tid = threadIdx.x;

    __shared__ float  sProb[Q_ * NCLS];   // softmax probs, classes 0..12
    __shared__ float  sLse[Q_];           // logsumexp per query (for CE)
    __shared__ float4 sPb4[Q_];           // predicted boxes
    __shared__ float4 sTb4[T_];           // target boxes
    __shared__ int    sLab[T_];           // target labels
    __shared__ double sU[T_ + 1];         // row duals (1-based)
    __shared__ int    sP[Q_ + 1];         // col -> assigned row (1-based), 0=free
    __shared__ int    sWay[Q_ + 1];       // Dijkstra back-pointers; reused as tc[]
    __shared__ int    sAmin[T_];          // row -> argmin column (0-based)
    __shared__ int    sFreeRows[FRSZ];
    __shared__ int    sNumFree;
    __shared__ int    sPred[T_];          // target t -> matched query
    __shared__ double sAcc[NWV];

    const double DINF = __builtin_inf();

    const float* pcb = pc  + (size_t)b * Q_ * NCLS1;
    const float* pbb = pbx + (size_t)b * Q_ * 4;
    const float* tbb = tbx + (size_t)b * T_ * 4;
    const int*   tlb = tl  + (size_t)b * T_;

    // ---- stage inputs + f32 softmax (same op order as jax.nn.softmax) ----
    for (int q = tid; q < Q_; q += NTH) {
        float x[NCLS1];
#pragma unroll
        for (int c = 0; c < NCLS1; ++c) x[c] = pcb[q * NCLS1 + c];
        float mx = x[0];
#pragma unroll
        for (int c = 1; c < NCLS1; ++c) mx = fmaxf(mx, x[c]);
        float ex[NCLS1];
        float sum = 0.f;
#pragma unroll
        for (int c = 0; c < NCLS1; ++c) { ex[c] = expf(x[c] - mx); sum += ex[c]; }
#pragma unroll
        for (int c = 0; c < NCLS; ++c) sProb[q * NCLS + c] = ex[c] / sum;
        sLse[q] = mx + logf(sum);
        sPb4[q] = reinterpret_cast<const float4*>(pbb)[q];
    }
    for (int t = tid; t < T_; t += NTH) {
        sLab[t] = tlb[t];
        sTb4[t] = reinterpret_cast<const float4*>(tbb)[t];
    }
    for (int j = tid; j <= Q_; j += NTH) sP[j] = 0;
    __syncthreads();

    // ---- phase 1: row minima (u[r] = min_j cost[r][j]) + argmin column ----
    {
        const int r    = tid >> 1;        // 0..127, two threads per row
        const int half = tid & 1;
        const float4 t4  = sTb4[r];
        const int    lab = sLab[r];
        float bv = __builtin_inff();
        int   bj = Q_;
        const int q0 = half * (Q_ / 2);
        for (int q = q0; q < q0 + (Q_ / 2); ++q) {
            const float c = costQ(sPb4[q], t4, sProb[q * NCLS + lab]);
            if (c < bv) { bv = c; bj = q; }
        }
        const float ov = __shfl_xor(bv, 1);
        const int   oj = __shfl_xor(bj, 1);
        if (ov < bv || (ov == bv && oj < bj)) { bv = ov; bj = oj; }
        if (half == 0) { sU[r + 1] = (double)bv; sAmin[r] = bj; }
    }
    __syncthreads();

    // ================= wave 0 only: greedy + ARR + Dijkstra =================
    if (tid < 64) {
        const int lane = tid;
        const unsigned validMask = (lane < (Q_ - 64 * (NK - 1))) ? ((1u << NK) - 1u)
                                                                 : ((1u << (NK - 1)) - 1u);
        // per-lane column state in registers
        float4 pbr[NK];
        double v[NK];
#pragma unroll
        for (int k = 0; k < NK; ++k) {
            const int q = (k << 6) + lane;
            pbr[k] = (q < Q_) ? sPb4[q] : make_float4(0.f, 0.f, 0.f, 0.f);
            v[k] = 0.0;
        }

        // ---- greedy zero-reduced-cost assignment (lane 0, serial) ----
        if (lane == 0) {
            int nf = 0;
            for (int r = 0; r < T_; ++r) {
                const int j = sAmin[r] + 1;
                if (sP[j] == 0) sP[j] = r + 1;
                else            sFreeRows[nf++] = r;
            }
            sNumFree = nf;
        }
        __builtin_amdgcn_wave_barrier();
        const int nf0 = sNumFree;
        int head = 0, tail = nf0;

        // ---- augmenting row reduction (capped); keeps feasibility+tightness ----
        {
            int steps = 0;
            const int cap = 2 * nf0;
            while (head < tail && steps < cap) {
                ++steps;
                const int r = sFreeRows[head]; ++head;
                const float4 t4  = sTb4[r];
                const int    lab = sLab[r];
                double m1 = DINF, m2 = DINF;
                int    j1 = Q_ + 1;
#pragma unroll
                for (int k = 0; k < NK; ++k) {
                    double cur = DINF;
                    const int q = (k << 6) + lane;
                    if ((validMask >> k) & 1u)
                        cur = (double)costQ(pbr[k], t4, sProb[q * NCLS + lab]) - v[k];
                    if (cur < m1)      { m2 = m1; m1 = cur; j1 = q + 1; }
                    else if (cur < m2) { m2 = cur; }
                }
                // butterfly merge of (min, argmin, 2nd-min); first-index ties
#pragma unroll
                for (int m = 1; m < 64; m <<= 1) {
                    const double om1 = __shfl_xor(m1, m);
                    const int    oj1 = __shfl_xor(j1, m);
                    const double om2 = __shfl_xor(m2, m);
                    if (om1 < m1 || (om1 == m1 && oj1 < j1)) {
                        m2 = fmin(m1, om2);
                        m1 = om1; j1 = oj1;
                    } else {
                        m2 = fmin(m2, om1);
                    }
                }
                const int owner = (j1 - 1) & 63;
                const int kidx  = (j1 - 1) >> 6;
                const int kold  = sP[j1];            // read before write; DS in-order
                if (lane == owner) { v[kidx] -= (m2 - m1); sP[j1] = r + 1; }
                if (lane == 0)     sU[r + 1] = m2;   // tight on j1 after v update
                if (kold != 0) {
                    if (lane == 0) sFreeRows[tail] = kold - 1;
                    ++tail;                          // redundant in all lanes
                }
                __builtin_amdgcn_wave_barrier();
            }
        }

        // ---- SSP Dijkstra for remaining free rows (no barriers, 1 wave) ----
        while (head < tail) {
            const int i = sFreeRows[head] + 1; ++head;
            double minv[NK];
#pragma unroll
            for (int k = 0; k < NK; ++k) minv[k] = DINF;
            unsigned used = ~validMask;
            int j0col = 0, i0 = i;
            for (;;) {
                if (j0col) {                          // mark previous j1 used
                    const int c = j0col - 1;
                    if ((c & 63) == lane) used |= 1u << (c >> 6);
                }
                const double u_i0 = sU[i0];           // untouched within this pass
                const float4 t4   = sTb4[i0 - 1];
                const int    lab  = sLab[i0 - 1];
                double bestv = DINF;
                int    bestj = Q_ + 1;
#pragma unroll
                for (int k = 0; k < NK; ++k) {
                    if (!((used >> k) & 1u)) {
                        const int q = (k << 6) + lane;
                        const double cur =
                            (double)costQ(pbr[k], t4, sProb[q * NCLS + lab]) - u_i0 - v[k];
                        if (cur < minv[k]) { minv[k] = cur; sWay[q + 1] = j0col; }
                        if (minv[k] < bestv) { bestv = minv[k]; bestj = q + 1; }
                    }
                }
#pragma unroll
                for (int m = 1; m < 64; m <<= 1) {
                    const double ov = __shfl_xor(bestv, m);
                    const int    oj = __shfl_xor(bestj, m);
                    if (ov < bestv || (ov == bestv && oj < bestj)) { bestv = ov; bestj = oj; }
                }
                const double delta = bestv;
                const int    dj    = bestj;
                // u[p[used]] += delta; v[used] -= delta; minv[free] -= delta
                const unsigned um = used & validMask;
#pragma unroll
                for (int k = 0; k < NK; ++k) {
                    if ((um >> k) & 1u) {
                        const int row = sP[(k << 6) + lane + 1];  // fixed owner lane RMW
                        sU[row] += delta;
                        v[k] -= delta;
                    } else if (!((used >> k) & 1u)) {
                        minv[k] -= delta;
                    }
                }
                if (lane == 0) sU[i] += delta;       // virtual column 0 (p[0]=i)
                const int pj1 = sP[dj];
                __builtin_amdgcn_wave_barrier();
                if (pj1 == 0) { j0col = dj; break; }
                j0col = dj; i0 = pj1;
            }
            if (lane == 0) {                         // augmenting path (short)
                int jj = j0col;
                while (jj != 0) {
                    const int jn = sWay[jj];
                    sP[jj] = (jn == 0) ? i : sP[jn];
                    jj = jn;
                }
            }
            __builtin_amdgcn_wave_barrier();
        }
    }
    __syncthreads();

    // ---- extract matching: pred query for each target ----
    for (int j = 1 + tid; j <= Q_; j += NTH) {
        const int pi = sP[j];
        if (pi > 0) sPred[pi - 1] = j - 1;
    }
    __syncthreads();

    // ---- tc[] (reuse sWay): NUM_CLASSES default, matched queries get label ----
    int* sTc = sWay;
    for (int q = tid; q < Q_; q += NTH) sTc[q] = NCLS;
    __syncthreads();
    for (int t = tid; t < T_; t += NTH) sTc[sPred[t]] = sLab[t];  // sPred distinct
    __syncthreads();

    // ---- weighted CE over all queries ----
    double swn = 0.0, sw = 0.0;
    for (int q = tid; q < Q_; q += NTH) {
        const int   c   = sTc[q];
        const float xv  = pcb[q * NCLS1 + c];
        const float nll = sLse[q] - xv;              // -log_softmax[tc]
        const double w  = (c == NCLS) ? (double)0.05f : 1.0;
        swn += w * (double)nll;
        sw  += w;
    }

    // ---- bbox L1 + GIoU over matched pairs ----
    double l1s = 0.0, gs = 0.0;
    for (int t = tid; t < T_; t += NTH) {
        const int q = sPred[t];
        const float4 p4 = sPb4[q];
        const float4 t4 = sTb4[t];
        l1s += (double)fabsf(p4.x - t4.x) + (double)fabsf(p4.y - t4.y)
             + (double)fabsf(p4.z - t4.z) + (double)fabsf(p4.w - t4.w);
        const float ax1 = p4.x - 0.5f * p4.z, ay1 = p4.y - 0.5f * p4.w;
        const float ax2 = p4.x + 0.5f * p4.z, ay2 = p4.y + 0.5f * p4.w;
        const float bx1 = t4.x - 0.5f * t4.z, by1 = t4.y - 0.5f * t4.w;
        const float bx2 = t4.x + 0.5f * t4.z, by2 = t4.y + 0.5f * t4.w;
        const double a1 = (double)(ax2 - ax1) * (double)(ay2 - ay1);
        const double a2 = (double)(bx2 - bx1) * (double)(by2 - by1);
        const double ltx = fmax((double)ax1, (double)bx1);
        const double lty = fmax((double)ay1, (double)by1);
        const double rbx = fmin((double)ax2, (double)bx2);
        const double rby = fmin((double)ay2, (double)by2);
        const double iw = fmax(rbx - ltx, 0.0), ih = fmax(rby - lty, 0.0);
        const double inter = iw * ih;
        const double uni   = a1 + a2 - inter;
        const double iou   = inter / uni;
        const double cx1 = fmin((double)ax1, (double)bx1);
        const double cy1 = fmin((double)ay1, (double)by1);
        const double cx2 = fmax((double)ax2, (double)bx2);
        const double cy2 = fmax((double)ay2, (double)by2);
        const double ac  = (cx2 - cx1) * (cy2 - cy1);
        const double giou = iou - (ac - uni) / ac;
        gs += 1.0 - giou;
    }

    const double swnT = blockSum(swn, sAcc, tid);
    const double swT  = blockSum(sw,  sAcc, tid);
    const double l1T  = blockSum(l1s, sAcc, tid);
    const double gsT  = blockSum(gs,  sAcc, tid);
    if (tid == 0) {
        const double cls = swnT / swT;
        const double bb  = 5.0 * (l1T / (double)(T_ * 4)) + 2.0 * (gsT / (double)T_);
        perImg[b] = cls + bb;
    }
}

extern "C" __global__ __launch_bounds__(64)
void detr_finalize(const double* __restrict__ perImg, float* __restrict__ out)
{
    const int l = threadIdx.x;   // 64 threads, one wave
    double v = perImg[l];
#pragma unroll
    for (int off = 32; off > 0; off >>= 1) v += __shfl_down(v, off);
    if (l == 0) out[0] = (float)(v / 8192.0);
}

extern "C" void kernel_launch(void* const* d_in, const int* in_sizes, int n_in,
                              void* d_out, int out_size, void* d_ws, size_t ws_size,
                              hipStream_t stream) {
    const float* pc  = (const float*)d_in[0];   // predicted_class [64,900,14]
    const float* pbx = (const float*)d_in[1];   // predicted_bbox  [64,900,4]
    const int*   tl  = (const int*)  d_in[2];   // target_labels   [64,128]
    const float* tbx = (const float*)d_in[3];   // target_boxes    [64,128,4]
    double* wsl = (double*)d_ws;                // 64 doubles of scratch
    (void)in_sizes; (void)n_in; (void)out_size; (void)ws_size;

    detr_hungarian_loss<<<dim3(B_), dim3(NTH), 0, stream>>>(pc, pbx, tl, tbx, wsl);
    detr_finalize<<<dim3(1), dim3(64), 0, stream>>>(wsl, (float*)d_out);
}